// Round 1
// 952.454 us; speedup vs baseline: 3.2767x; 3.2767x over previous
//
#include <hip/hip_runtime.h>
#include <stdint.h>

typedef unsigned short u16;
typedef unsigned int u32;
typedef __attribute__((ext_vector_type(8))) short s16x8;   // 8 bf16 (4 VGPRs) MFMA frag
typedef __attribute__((ext_vector_type(4))) float f32x4;   // MFMA accum

// ---------- bf16 helpers ----------
__device__ __forceinline__ u16 f2bf(float f) {
  union { float f; u32 u; } v; v.f = f;
  u32 u = v.u;
  return (u16)((u + 0x7fffu + ((u >> 16) & 1u)) >> 16);
}
__device__ __forceinline__ float bf2f_lo(u32 u) {
  union { u32 uu; float f; } v; v.uu = u << 16; return v.f;
}
__device__ __forceinline__ float bf2f_hi(u32 u) {
  union { u32 uu; float f; } v; v.uu = u & 0xffff0000u; return v.f;
}
__device__ __forceinline__ void cvt8(uint4 w, float* f) {
  f[0] = bf2f_lo(w.x); f[1] = bf2f_hi(w.x);
  f[2] = bf2f_lo(w.y); f[3] = bf2f_hi(w.y);
  f[4] = bf2f_lo(w.z); f[5] = bf2f_hi(w.z);
  f[6] = bf2f_lo(w.w); f[7] = bf2f_hi(w.w);
}

// ---------- constants ----------
#define NT 49        // tokens per window
#define CD 256       // dim
#define NWIN 4096    // 64 imgs * 64 windows
#define SA_RS 260    // kn f32 row stride
#define SB_RS 520    // q|k bf16 row stride (q cols 0..255, k 256..511, +8 pad)
#define SV_RS 260    // v f32 row stride
#define SX_RS 264    // x / attn-out bf16 row stride (264*2B=528B -> 8-lane/4-bank uniform)

// workspace offsets (bytes)
#define WS_RPBT  8192
#define WS_MASKT (8192 + 80000)
#define WS_WQKV  704512
#define WS_WPROJ (704512 + 393216)

// =====================================================================
// Kernel A: CPB MLP: table[p*8+h]
// =====================================================================
__global__ void cpb_table_kernel(const float* __restrict__ coords,
                                 const float* __restrict__ w1,
                                 const float* __restrict__ b1,
                                 const float* __restrict__ w2,
                                 float* __restrict__ table) {
  int t = blockIdx.x * 256 + threadIdx.x;
  if (t >= 169 * 8) return;
  int p = t >> 3, h = t & 7;
  float c0 = coords[p * 2], c1 = coords[p * 2 + 1];
  float acc = 0.f;
  for (int j = 0; j < 512; ++j) {
    float hid = fmaf(c0, w1[j * 2], fmaf(c1, w1[j * 2 + 1], b1[j]));
    hid = fmaxf(hid, 0.f);
    acc = fmaf(hid, w2[h * 512 + j], acc);
  }
  table[t] = acc;
}

// =====================================================================
// Kernel B: rpbT / maskT prep (i-fast layouts)
// =====================================================================
__global__ void bias_prep_kernel(const float* __restrict__ table,
                                 const int* __restrict__ rpi,
                                 const float* __restrict__ mask,
                                 float* __restrict__ rpbT,
                                 float* __restrict__ maskT) {
  int idx = blockIdx.x * 256 + threadIdx.x;
  if (idx < 8 * 2401) {
    int h = idx / 2401;
    int r = idx - h * 2401;
    int j = r / 49, i = r - j * 49;
    float v = table[rpi[i * 49 + j] * 8 + h];
    rpbT[idx] = 16.f / (1.f + __expf(-v));
  } else if (idx < 8 * 2401 + 64 * 2401) {
    int k = idx - 8 * 2401;
    int w = k / 2401;
    int r = k - w * 2401;
    int j = r / 49, i = r - j * 49;
    maskT[k] = mask[w * 2401 + i * 49 + j];
  }
}

// =====================================================================
// Kernel C: weights f32 -> bf16, pre-swizzled into MFMA B-fragment order.
// Layout: frag[ntile][kk][lane][8] ; value = W[ntile*16 + (lane&15)]
//                                          [kk*32 + (lane>>4)*8 + j]
// qkv_w: 48 ntiles, proj_w: 16 ntiles; 8 ksteps of 32 each.
// =====================================================================
__global__ void wcvt_kernel(const float* __restrict__ qkv_w,
                            const float* __restrict__ proj_w,
                            u16* __restrict__ wq, u16* __restrict__ wp) {
  int t = blockIdx.x * 256 + threadIdx.x;
  if (t >= 32768) return;
  const float* src; u16* dst; int idx;
  if (t < 24576) { idx = t; src = qkv_w; dst = wq + (size_t)idx * 8; }
  else           { idx = t - 24576; src = proj_w; dst = wp + (size_t)idx * 8; }
  int nt = idx >> 9, rem = idx & 511;
  int kk = rem >> 6, l = rem & 63;
  int n = nt * 16 + (l & 15);
  int k = kk * 32 + (l >> 4) * 8;
  const float4* s = (const float4*)(src + (size_t)n * 256 + k);
  float4 v0 = s[0], v1 = s[1];
  u32 w0 = (u32)f2bf(v0.x) | ((u32)f2bf(v0.y) << 16);
  u32 w1 = (u32)f2bf(v0.z) | ((u32)f2bf(v0.w) << 16);
  u32 w2 = (u32)f2bf(v1.x) | ((u32)f2bf(v1.y) << 16);
  u32 w3 = (u32)f2bf(v1.z) | ((u32)f2bf(v1.w) << 16);
  *(uint4*)dst = make_uint4(w0, w1, w2, w3);
}

// =====================================================================
// Fused per-window kernel (512 threads = 8 waves):
//   P1 x->LDS bf16 ; P2 qkv via MFMA ; P3 cosine attn (VALU, unchanged) ;
//   P4 proj via MFMA.
// =====================================================================
__global__ __launch_bounds__(512) void swin_fused(
    const float* __restrict__ x,
    const float* __restrict__ q_bias, const float* __restrict__ v_bias,
    const float* __restrict__ logit_scale,
    const float* __restrict__ rpbT, const float* __restrict__ maskT,
    const u16* __restrict__ wq, const u16* __restrict__ wp,
    const float* __restrict__ proj_b,
    float* __restrict__ out) {
  // region0: x bf16 [64][264] -> kn f32 [49][260] -> attn-out bf16 [49..][264]
  // region1: q|k bf16 [49][520]
  // region2: v f32 [49][260]
  __shared__ __attribute__((aligned(16))) unsigned char smem[156000];
  float* sA = (float*)smem;                 // kn (f32)
  u16*   sX = (u16*)smem;                   // x / attn-out (bf16)
  u16*   sB = (u16*)(smem + 52000);         // q,k (bf16)
  float* sV = (float*)(smem + 104000);      // v (f32)

  const int tid = threadIdx.x;
  const int wid = blockIdx.x;
  const int wimg = wid & 63;
  const int hh = tid >> 6;   // wave / head
  const int il = tid & 63;   // lane / row
  const int lr = il & 15;    // MFMA frag row/col within tile
  const int lg = il >> 4;    // MFMA frag k-group / row-group

  // ---- Phase 1: x (f32) -> sX bf16 rows 0..48 ----
  {
    const float4* xg = (const float4*)(x + (size_t)wid * (NT * CD));
    for (int e = tid; e < (NT * CD) / 4; e += 512) {
      int row = e >> 6, c4 = e & 63;
      float4 v = xg[e];
      u32 w0 = (u32)f2bf(v.x) | ((u32)f2bf(v.y) << 16);
      u32 w1 = (u32)f2bf(v.z) | ((u32)f2bf(v.w) << 16);
      *(uint2*)&sX[row * SX_RS + c4 * 4] = make_uint2(w0, w1);
    }
  }
  __syncthreads();

  // ---- Phase 2: qkv = x @ qkv_w^T + bias via MFMA (wave hh: n-cols hh*96..hh*96+95)
  // Pad rows 49..63 of sX are stale garbage: MFMA is row-local, rows >=49 masked below.
  {
    f32x4 acc[6][4];
#pragma unroll
    for (int nt = 0; nt < 6; ++nt)
#pragma unroll
      for (int mt = 0; mt < 4; ++mt) acc[nt][mt] = (f32x4){0.f, 0.f, 0.f, 0.f};
    const u16* wqb = wq + (size_t)hh * 24576 + il * 8;  // (hh*6 ntiles)*8kk*512
#pragma unroll 2
    for (int kk = 0; kk < 8; ++kk) {
      s16x8 a[4], b[6];
#pragma unroll
      for (int mt = 0; mt < 4; ++mt)
        a[mt] = *(const s16x8*)&sX[(mt * 16 + lr) * SX_RS + kk * 32 + lg * 8];
#pragma unroll
      for (int nt = 0; nt < 6; ++nt)
        b[nt] = *(const s16x8*)&wqb[(nt * 8 + kk) * 512];
#pragma unroll
      for (int nt = 0; nt < 6; ++nt)
#pragma unroll
        for (int mt = 0; mt < 4; ++mt)
          acc[nt][mt] = __builtin_amdgcn_mfma_f32_16x16x32_bf16(
              a[mt], b[nt], acc[nt][mt], 0, 0, 0);
    }
    // epilogue: C col = lane&15, row = 4*(lane>>4)+i (verified layout)
#pragma unroll
    for (int nt = 0; nt < 6; ++nt) {
      const int n0 = hh * 96 + nt * 16;     // global qkv output column base
      const int r = n0 >> 8;                // 0=q, 1=k, 2=v (wave-uniform)
      const int c0 = (n0 & 255) + lr;
      const float bias = (r == 0) ? q_bias[c0] : ((r == 2) ? v_bias[c0] : 0.f);
#pragma unroll
      for (int mt = 0; mt < 4; ++mt) {
#pragma unroll
        for (int i = 0; i < 4; ++i) {
          const int row = mt * 16 + lg * 4 + i;
          if (row < NT) {
            const float val = acc[nt][mt][i] + bias;
            if (r == 0)      sB[row * SB_RS + c0] = f2bf(val);
            else if (r == 1) sB[row * SB_RS + 256 + c0] = f2bf(val);
            else             sV[row * SV_RS + c0] = val;
          }
        }
      }
    }
  }
  __syncthreads();

  // ---- Phase 3: per (head, row) task; head uniform per wave (unchanged VALU path)
  const bool act = il < NT;

  // 3a: normalized K -> sA (overwrites x region; all P2 sX reads done at barrier)
  if (act) {
    const uint4* kb = (const uint4*)&sB[il * SB_RS + 256 + hh * 32];
    float kf[32];
#pragma unroll
    for (int cgrp = 0; cgrp < 4; ++cgrp) { uint4 t4 = kb[cgrp]; cvt8(t4, &kf[cgrp * 8]); }
    float ss = 1e-6f;
#pragma unroll
    for (int d = 0; d < 32; ++d) ss = fmaf(kf[d], kf[d], ss);
    const float rk = rsqrtf(ss);
    float4* dst = (float4*)&sA[il * SA_RS + hh * 32];
#pragma unroll
    for (int cgrp = 0; cgrp < 8; ++cgrp)
      dst[cgrp] = make_float4(kf[cgrp * 4] * rk, kf[cgrp * 4 + 1] * rk,
                              kf[cgrp * 4 + 2] * rk, kf[cgrp * 4 + 3] * rk);
  }
  __syncthreads();

  // 3b: scores + softmax (p stays in registers across the barrier)
  float p[49];
  float inv = 0.f;
  if (act) {
    const float scl = __expf(fminf(logit_scale[hh], 4.605170186f));
    const uint4* qb = (const uint4*)&sB[il * SB_RS + hh * 32];
    float qf[32];
#pragma unroll
    for (int cgrp = 0; cgrp < 4; ++cgrp) { uint4 t4 = qb[cgrp]; cvt8(t4, &qf[cgrp * 8]); }
    float ss = 1e-6f;
#pragma unroll
    for (int d = 0; d < 32; ++d) ss = fmaf(qf[d], qf[d], ss);
    const float qs = rsqrtf(ss) * scl;
#pragma unroll
    for (int d = 0; d < 32; ++d) qf[d] *= qs;
    const float* rpb_b = rpbT + hh * 2401 + il;
    const float* msk_b = maskT + wimg * 2401 + il;
    float mx = -1e30f;
#pragma unroll
    for (int j = 0; j < 49; ++j) {
      const float4* kr = (const float4*)&sA[j * SA_RS + hh * 32];
      float s0 = 0.f, s1 = 0.f, s2 = 0.f, s3 = 0.f;
#pragma unroll
      for (int cgrp = 0; cgrp < 8; ++cgrp) {
        float4 kv = kr[cgrp];
        s0 = fmaf(qf[cgrp * 4 + 0], kv.x, s0);
        s1 = fmaf(qf[cgrp * 4 + 1], kv.y, s1);
        s2 = fmaf(qf[cgrp * 4 + 2], kv.z, s2);
        s3 = fmaf(qf[cgrp * 4 + 3], kv.w, s3);
      }
      float pv = (s0 + s1) + (s2 + s3) + rpb_b[j * 49] + msk_b[j * 49];
      p[j] = pv;
      mx = fmaxf(mx, pv);
    }
    float sum = 0.f;
#pragma unroll
    for (int j = 0; j < 49; ++j) { float e = __expf(p[j] - mx); p[j] = e; sum += e; }
    inv = 1.0f / sum;
  }
  __syncthreads();  // all kn reads done before attn-out overwrites region0

  // 3c: attn-out = (p/sum) @ v -> sX as bf16 (MFMA A-layout for P4)
  if (act) {
    float o[32];
#pragma unroll
    for (int d = 0; d < 32; ++d) o[d] = 0.f;
    for (int j = 0; j < 49; ++j) {
      const float4* vb = (const float4*)&sV[j * SV_RS + hh * 32];
      const float pj = p[j];
#pragma unroll
      for (int cgrp = 0; cgrp < 8; ++cgrp) {
        float4 vv = vb[cgrp];
        o[cgrp * 4 + 0] = fmaf(pj, vv.x, o[cgrp * 4 + 0]);
        o[cgrp * 4 + 1] = fmaf(pj, vv.y, o[cgrp * 4 + 1]);
        o[cgrp * 4 + 2] = fmaf(pj, vv.z, o[cgrp * 4 + 2]);
        o[cgrp * 4 + 3] = fmaf(pj, vv.w, o[cgrp * 4 + 3]);
      }
    }
#pragma unroll
    for (int cg = 0; cg < 4; ++cg) {
      u32 b0 = (u32)f2bf(o[cg * 8 + 0] * inv) | ((u32)f2bf(o[cg * 8 + 1] * inv) << 16);
      u32 b1 = (u32)f2bf(o[cg * 8 + 2] * inv) | ((u32)f2bf(o[cg * 8 + 3] * inv) << 16);
      u32 b2 = (u32)f2bf(o[cg * 8 + 4] * inv) | ((u32)f2bf(o[cg * 8 + 5] * inv) << 16);
      u32 b3 = (u32)f2bf(o[cg * 8 + 6] * inv) | ((u32)f2bf(o[cg * 8 + 7] * inv) << 16);
      *(uint4*)&sX[il * SX_RS + hh * 32 + cg * 8] = make_uint4(b0, b1, b2, b3);
    }
  }
  __syncthreads();

  // ---- Phase 4: out = attn_out @ proj_w^T + proj_b via MFMA (wave hh: cols hh*32..)
  {
    f32x4 acc[2][4];
#pragma unroll
    for (int nt = 0; nt < 2; ++nt)
#pragma unroll
      for (int mt = 0; mt < 4; ++mt) acc[nt][mt] = (f32x4){0.f, 0.f, 0.f, 0.f};
    const u16* wpb = wp + (size_t)hh * 8192 + il * 8;  // (hh*2 ntiles)*8kk*512
#pragma unroll 2
    for (int kk = 0; kk < 8; ++kk) {
      s16x8 a[4], b[2];
#pragma unroll
      for (int mt = 0; mt < 4; ++mt)
        a[mt] = *(const s16x8*)&sX[(mt * 16 + lr) * SX_RS + kk * 32 + lg * 8];
#pragma unroll
      for (int nt = 0; nt < 2; ++nt)
        b[nt] = *(const s16x8*)&wpb[(nt * 8 + kk) * 512];
#pragma unroll
      for (int nt = 0; nt < 2; ++nt)
#pragma unroll
        for (int mt = 0; mt < 4; ++mt)
          acc[nt][mt] = __builtin_amdgcn_mfma_f32_16x16x32_bf16(
              a[mt], b[nt], acc[nt][mt], 0, 0, 0);
    }
    float* og = out + (size_t)wid * (NT * CD);
#pragma unroll
    for (int nt = 0; nt < 2; ++nt) {
      const int col = hh * 32 + nt * 16 + lr;
      const float bias = proj_b[col];
#pragma unroll
      for (int mt = 0; mt < 4; ++mt) {
#pragma unroll
        for (int i = 0; i < 4; ++i) {
          const int row = mt * 16 + lg * 4 + i;
          if (row < NT) og[row * CD + col] = acc[nt][mt][i] + bias;
        }
      }
    }
  }
}

extern "C" void kernel_launch(void* const* d_in, const int* in_sizes, int n_in,
                              void* d_out, int out_size, void* d_ws, size_t ws_size,
                              hipStream_t stream) {
  (void)in_sizes; (void)n_in; (void)out_size; (void)ws_size;
  const float* x           = (const float*)d_in[0];
  const float* qkv_w       = (const float*)d_in[1];
  const float* q_bias      = (const float*)d_in[2];
  const float* v_bias      = (const float*)d_in[3];
  const float* logit_scale = (const float*)d_in[4];
  const float* cpb_w1      = (const float*)d_in[5];
  const float* cpb_b1      = (const float*)d_in[6];
  const float* cpb_w2      = (const float*)d_in[7];
  const float* coords      = (const float*)d_in[8];
  const int*   rpi         = (const int*)d_in[9];
  const float* mask        = (const float*)d_in[10];
  const float* proj_w      = (const float*)d_in[11];
  const float* proj_b      = (const float*)d_in[12];
  float* out = (float*)d_out;

  float* table = (float*)d_ws;                         // 169*8 f32
  float* rpbT  = (float*)((char*)d_ws + WS_RPBT);      // 8*2401 f32
  float* maskT = (float*)((char*)d_ws + WS_MASKT);     // 64*2401 f32
  u16*   wq    = (u16*)((char*)d_ws + WS_WQKV);        // 48*8*64*8 bf16 (384 KB)
  u16*   wp    = (u16*)((char*)d_ws + WS_WPROJ);       // 16*8*64*8 bf16 (128 KB)

  hipLaunchKernelGGL(cpb_table_kernel, dim3(6), dim3(256), 0, stream,
                     coords, cpb_w1, cpb_b1, cpb_w2, table);
  hipLaunchKernelGGL(bias_prep_kernel, dim3((8 * 2401 + 64 * 2401 + 255) / 256),
                     dim3(256), 0, stream, table, rpi, mask, rpbT, maskT);
  hipLaunchKernelGGL(wcvt_kernel, dim3(128), dim3(256), 0, stream,
                     qkv_w, proj_w, wq, wp);
  hipLaunchKernelGGL(swin_fused, dim3(NWIN), dim3(512), 0, stream,
                     x, q_bias, v_bias, logit_scale, rpbT, maskT,
                     wq, wp, proj_b, out);
}

// Round 2
// 732.216 us; speedup vs baseline: 4.2622x; 1.3008x over previous
//
#include <hip/hip_runtime.h>
#include <stdint.h>

typedef unsigned short u16;
typedef unsigned int u32;
typedef __attribute__((ext_vector_type(8))) short s16x8;   // 8 bf16 (4 VGPRs) MFMA frag
typedef __attribute__((ext_vector_type(4))) float f32x4;   // MFMA accum / vec4

// ---------- bf16 helpers ----------
__device__ __forceinline__ u16 f2bf(float f) {
  union { float f; u32 u; } v; v.f = f;
  u32 u = v.u;
  return (u16)((u + 0x7fffu + ((u >> 16) & 1u)) >> 16);
}
__device__ __forceinline__ float bf2f_lo(u32 u) {
  union { u32 uu; float f; } v; v.uu = u << 16; return v.f;
}
__device__ __forceinline__ float bf2f_hi(u32 u) {
  union { u32 uu; float f; } v; v.uu = u & 0xffff0000u; return v.f;
}
__device__ __forceinline__ void cvt8(uint4 w, float* f) {
  f[0] = bf2f_lo(w.x); f[1] = bf2f_hi(w.x);
  f[2] = bf2f_lo(w.y); f[3] = bf2f_hi(w.y);
  f[4] = bf2f_lo(w.z); f[5] = bf2f_hi(w.z);
  f[6] = bf2f_lo(w.w); f[7] = bf2f_hi(w.w);
}

// ---------- constants ----------
#define NT 49        // tokens per window
#define CD 256       // dim
#define NWIN 4096    // 64 imgs * 64 windows
#define SB_RS 520    // q|k bf16 row stride (q cols 0..255, k 256..511, +8 pad)
#define SX_RS 264    // x / attn-out bf16 row stride
#define SVT_RS 72    // V^T kv stride (64 kv + 8 pad)

// LDS offsets (bytes)
#define L_SX  0                      // [64][264] bf16 = 33792
#define L_SB  33792                  // [64][520] bf16 = 66560
#define L_SVT 100352                 // [256 d][72 kv] bf16 = 36864
#define L_SRQ 137216                 // [8][64] f32
#define L_SRK 139264                 // [8][64] f32
#define L_SINV 141312                // [8][64] f32
#define L_TOTAL 143360

// workspace offsets (bytes)
#define WS_RPB64 8192                        // 8*64*64 f32 = 131072
#define WS_MSK64 (8192 + 131072)             // 64*64*64 f32 = 1048576
#define WS_WQKV  (139264 + 1048576)          // 1187840: 384 KB
#define WS_WPROJ (1187840 + 393216)          // 1581056: 128 KB

// =====================================================================
// Kernel A: CPB MLP: table[p*8+h]
// =====================================================================
__global__ void cpb_table_kernel(const float* __restrict__ coords,
                                 const float* __restrict__ w1,
                                 const float* __restrict__ b1,
                                 const float* __restrict__ w2,
                                 float* __restrict__ table) {
  int t = blockIdx.x * 256 + threadIdx.x;
  if (t >= 169 * 8) return;
  int p = t >> 3, h = t & 7;
  float c0 = coords[p * 2], c1 = coords[p * 2 + 1];
  float acc = 0.f;
  for (int j = 0; j < 512; ++j) {
    float hid = fmaf(c0, w1[j * 2], fmaf(c1, w1[j * 2 + 1], b1[j]));
    hid = fmaxf(hid, 0.f);
    acc = fmaf(hid, w2[h * 512 + j], acc);
  }
  table[t] = acc;
}

// =====================================================================
// Kernel B: padded 64x64 bias tables in the S^T C-layout-friendly order.
//   rpb64[h][q][kv] = 16*sigmoid(table[rpi[q][kv]][h])  (0 on pads)
//   mask64[w][q][kv] = mask[w][q][kv], with kv>=49 or q>=49 -> -1e9
// =====================================================================
__global__ void bias64_prep(const float* __restrict__ table,
                            const int* __restrict__ rpi,
                            const float* __restrict__ mask,
                            float* __restrict__ rpb64,
                            float* __restrict__ mask64) {
  int idx = blockIdx.x * 256 + threadIdx.x;
  if (idx < 8 * 4096) {
    int h = idx >> 12; int r = idx & 4095; int q = r >> 6, kv = r & 63;
    float v = 0.f;
    if (q < 49 && kv < 49) {
      float t = table[rpi[q * 49 + kv] * 8 + h];
      v = 16.f / (1.f + __expf(-t));
    }
    rpb64[idx] = v;
  } else if (idx < 8 * 4096 + 64 * 4096) {
    int k = idx - 8 * 4096;
    int w = k >> 12; int r = k & 4095; int q = r >> 6, kv = r & 63;
    float v = -1e9f;
    if (q < 49 && kv < 49) v = mask[w * 2401 + q * 49 + kv];
    mask64[k] = v;
  }
}

// =====================================================================
// Kernel C: weights f32 -> bf16, pre-swizzled into MFMA B-fragment order.
// frag[ntile][kk][lane][8]; value = W[nt*16+(l&15)][kk*32+(l>>4)*8+j]
// =====================================================================
__global__ void wcvt_kernel(const float* __restrict__ qkv_w,
                            const float* __restrict__ proj_w,
                            u16* __restrict__ wq, u16* __restrict__ wp) {
  int t = blockIdx.x * 256 + threadIdx.x;
  if (t >= 32768) return;
  const float* src; u16* dst; int idx;
  if (t < 24576) { idx = t; src = qkv_w; dst = wq + (size_t)idx * 8; }
  else           { idx = t - 24576; src = proj_w; dst = wp + (size_t)idx * 8; }
  int nt = idx >> 9, rem = idx & 511;
  int kk = rem >> 6, l = rem & 63;
  int n = nt * 16 + (l & 15);
  int k = kk * 32 + (l >> 4) * 8;
  const float4* s = (const float4*)(src + (size_t)n * 256 + k);
  float4 v0 = s[0], v1 = s[1];
  u32 w0 = (u32)f2bf(v0.x) | ((u32)f2bf(v0.y) << 16);
  u32 w1 = (u32)f2bf(v0.z) | ((u32)f2bf(v0.w) << 16);
  u32 w2 = (u32)f2bf(v1.x) | ((u32)f2bf(v1.y) << 16);
  u32 w3 = (u32)f2bf(v1.z) | ((u32)f2bf(v1.w) << 16);
  *(uint4*)dst = make_uint4(w0, w1, w2, w3);
}

// =====================================================================
// Fused per-window kernel (512 threads = 8 waves):
//   P1 x->LDS bf16 + zero pads ; P2 qkv via MFMA (v -> V^T bf16) ;
//   P3 attention fully via MFMA (S^T form) ; P4 proj via MFMA.
// =====================================================================
__global__ __launch_bounds__(512, 2) void swin_fused(
    const float* __restrict__ x,
    const float* __restrict__ q_bias, const float* __restrict__ v_bias,
    const float* __restrict__ logit_scale,
    const float* __restrict__ rpb64, const float* __restrict__ mask64,
    const u16* __restrict__ wq, const u16* __restrict__ wp,
    const float* __restrict__ proj_b,
    float* __restrict__ out) {
  __shared__ __attribute__((aligned(16))) unsigned char smem[L_TOTAL];
  u16*   sX  = (u16*)(smem + L_SX);    // x (P1-P2) / attn-out (P3c-P4), bf16
  u16*   sB  = (u16*)(smem + L_SB);    // q (cols 0..255) | k (256..511), bf16
  u16*   sVT = (u16*)(smem + L_SVT);   // V^T [d=256][72], bf16, pad kv zeroed
  float* sRQ = (float*)(smem + L_SRQ); // rsqrt(q.q)+scale per (h,row)
  float* sRK = (float*)(smem + L_SRK);
  float* sINV= (float*)(smem + L_SINV);

  const int tid = threadIdx.x;
  const int wid = blockIdx.x;
  const int wimg = wid & 63;
  const int hh = tid >> 6;   // wave / head
  const int il = tid & 63;   // lane
  const int lr = il & 15;    // MFMA frag row/col within tile
  const int lg = il >> 4;    // MFMA frag k-group / row-group

  // ---- Phase 1: x (f32) -> sX bf16 rows 0..48 ; zero sB pad rows + sVT ----
  {
    const float4* xg = (const float4*)(x + (size_t)wid * (NT * CD));
    for (int e = tid; e < (NT * CD) / 4; e += 512) {
      int row = e >> 6, c4 = e & 63;
      float4 v = xg[e];
      u32 w0 = (u32)f2bf(v.x) | ((u32)f2bf(v.y) << 16);
      u32 w1 = (u32)f2bf(v.z) | ((u32)f2bf(v.w) << 16);
      *(uint2*)&sX[row * SX_RS + c4 * 4] = make_uint2(w0, w1);
    }
    u32* zb = (u32*)&sB[49 * SB_RS];          // 15 rows * 520 u16 = 3900 u32
    for (int e = tid; e < 3900; e += 512) zb[e] = 0;
    u32* zv = (u32*)sVT;                      // 256*72 u16 = 9216 u32
    for (int e = tid; e < 9216; e += 512) zv[e] = 0;
  }
  __syncthreads();

  // ---- Phase 2: qkv = x @ qkv_w^T + bias via MFMA (wave hh: cols hh*96..+95)
  {
    f32x4 acc[6][4];
#pragma unroll
    for (int nt = 0; nt < 6; ++nt)
#pragma unroll
      for (int mt = 0; mt < 4; ++mt) acc[nt][mt] = (f32x4){0.f, 0.f, 0.f, 0.f};
    const u16* wqb = wq + (size_t)hh * 24576 + il * 8;
#pragma unroll 2
    for (int kk = 0; kk < 8; ++kk) {
      s16x8 a[4], b[6];
#pragma unroll
      for (int mt = 0; mt < 4; ++mt)
        a[mt] = *(const s16x8*)&sX[(mt * 16 + lr) * SX_RS + kk * 32 + lg * 8];
#pragma unroll
      for (int nt = 0; nt < 6; ++nt)
        b[nt] = *(const s16x8*)&wqb[(nt * 8 + kk) * 512];
#pragma unroll
      for (int nt = 0; nt < 6; ++nt)
#pragma unroll
        for (int mt = 0; mt < 4; ++mt)
          acc[nt][mt] = __builtin_amdgcn_mfma_f32_16x16x32_bf16(
              a[mt], b[nt], acc[nt][mt], 0, 0, 0);
    }
    // epilogue: C col = lane&15, row = 4*(lane>>4)+i
#pragma unroll
    for (int nt = 0; nt < 6; ++nt) {
      const int n0 = hh * 96 + nt * 16;
      const int r = n0 >> 8;                // 0=q, 1=k, 2=v (wave-uniform)
      const int c0 = (n0 & 255) + lr;
      if (r == 2) {
        const float bv = v_bias[c0];
        u16* vtb = &sVT[c0 * SVT_RS];       // V^T row d = c0
#pragma unroll
        for (int mt = 0; mt < 4; ++mt) {
          const int row0 = mt * 16 + lg * 4;
          float v0 = acc[nt][mt][0] + bv, v1 = acc[nt][mt][1] + bv;
          float v2 = acc[nt][mt][2] + bv, v3 = acc[nt][mt][3] + bv;
          if (mt < 3) {
            uint2 pk2;
            pk2.x = (u32)f2bf(v0) | ((u32)f2bf(v1) << 16);
            pk2.y = (u32)f2bf(v2) | ((u32)f2bf(v3) << 16);
            *(uint2*)&vtb[row0] = pk2;
          } else {
            if (row0     < NT) vtb[row0]     = f2bf(v0);
            if (row0 + 1 < NT) vtb[row0 + 1] = f2bf(v1);
            if (row0 + 2 < NT) vtb[row0 + 2] = f2bf(v2);
            if (row0 + 3 < NT) vtb[row0 + 3] = f2bf(v3);
          }
        }
      } else {
        const float bias = (r == 0) ? q_bias[c0] : 0.f;
        const int cb = (r == 0) ? c0 : (256 + c0);
#pragma unroll
        for (int mt = 0; mt < 4; ++mt) {
#pragma unroll
          for (int i = 0; i < 4; ++i) {
            const int row = mt * 16 + lg * 4 + i;
            if (row < NT) sB[row * SB_RS + cb] = f2bf(acc[nt][mt][i] + bias);
          }
        }
      }
    }
  }
  __syncthreads();

  // ---- Phase 3a: per-row inverse norms (rq includes logit scale) ----
  {
    float rqs = 0.f, rkv = 0.f;
    if (il < NT) {
      const float scl = __expf(fminf(logit_scale[hh], 4.605170186f));
      const uint4* qb4 = (const uint4*)&sB[il * SB_RS + hh * 32];
      const uint4* kb4 = (const uint4*)&sB[il * SB_RS + 256 + hh * 32];
      float f[8];
      float sq = 1e-6f, sk = 1e-6f;
#pragma unroll
      for (int c = 0; c < 4; ++c) {
        cvt8(qb4[c], f);
#pragma unroll
        for (int j = 0; j < 8; ++j) sq = fmaf(f[j], f[j], sq);
      }
#pragma unroll
      for (int c = 0; c < 4; ++c) {
        cvt8(kb4[c], f);
#pragma unroll
        for (int j = 0; j < 8; ++j) sk = fmaf(f[j], f[j], sk);
      }
      rqs = rsqrtf(sq) * scl;
      rkv = rsqrtf(sk);
    }
    sRQ[hh * 64 + il] = rqs;   // pad rows -> 0 (kills pad kv columns)
    sRK[hh * 64 + il] = rkv;
  }
  __syncthreads();

  // ---- Phase 3b/c: S^T via MFMA -> softmax in C-layout -> PV via MFMA ----
  {
    const int h = hh;
    // bias tiles (global, L2/L3-resident): B[q=lr+16nt][kv=16mt+4lg+i]
    const float* rpbp = rpb64 + h * 4096;
    const float* mskp = mask64 + wimg * 4096;
    f32x4 bias[4][4];
#pragma unroll
    for (int nt = 0; nt < 4; ++nt)
#pragma unroll
      for (int mt = 0; mt < 4; ++mt) {
        const int off = (lr + 16 * nt) * 64 + 16 * mt + 4 * lg;
        bias[nt][mt] = *(const f32x4*)(rpbp + off) + *(const f32x4*)(mskp + off);
      }
    // S^T = mfma(k_frag, q_frag): D[m=kv][n=q]
    s16x8 ka[4], qb[4];
#pragma unroll
    for (int mt = 0; mt < 4; ++mt)
      ka[mt] = *(const s16x8*)&sB[(lr + 16 * mt) * SB_RS + 256 + h * 32 + lg * 8];
#pragma unroll
    for (int nt = 0; nt < 4; ++nt)
      qb[nt] = *(const s16x8*)&sB[(lr + 16 * nt) * SB_RS + h * 32 + lg * 8];
    f32x4 sacc[4][4];   // [nt(q-tile)][mt(kv-tile)]
#pragma unroll
    for (int nt = 0; nt < 4; ++nt)
#pragma unroll
      for (int mt = 0; mt < 4; ++mt)
        sacc[nt][mt] = __builtin_amdgcn_mfma_f32_16x16x32_bf16(
            ka[mt], qb[nt], (f32x4){0.f, 0.f, 0.f, 0.f}, 0, 0, 0);
    // scale + bias + softmax; lane holds q=lr+16nt, kv=4lg+i+16mt
    f32x4 rk4[4];
#pragma unroll
    for (int mt = 0; mt < 4; ++mt)
      rk4[mt] = *(const f32x4*)&sRK[h * 64 + 16 * mt + 4 * lg];
#pragma unroll
    for (int nt = 0; nt < 4; ++nt) {
      const float rq_ = sRQ[h * 64 + lr + 16 * nt];
      float mx = -3e38f;
#pragma unroll
      for (int mt = 0; mt < 4; ++mt)
#pragma unroll
        for (int i = 0; i < 4; ++i) {
          float t = fmaf(sacc[nt][mt][i] * rk4[mt][i], rq_, bias[nt][mt][i]);
          sacc[nt][mt][i] = t;
          mx = fmaxf(mx, t);
        }
      mx = fmaxf(mx, __shfl_xor(mx, 16, 64));
      mx = fmaxf(mx, __shfl_xor(mx, 32, 64));
      float sm = 0.f;
#pragma unroll
      for (int mt = 0; mt < 4; ++mt)
#pragma unroll
        for (int i = 0; i < 4; ++i) {
          float e = __expf(sacc[nt][mt][i] - mx);
          sacc[nt][mt][i] = e;
          sm += e;
        }
      sm += __shfl_xor(sm, 16, 64);
      sm += __shfl_xor(sm, 32, 64);
      if (lg == 0) sINV[h * 64 + lr + 16 * nt] = 1.0f / sm;
    }
    // pack P to bf16 pairs
    u32 pkk[4][4][2];
#pragma unroll
    for (int nt = 0; nt < 4; ++nt)
#pragma unroll
      for (int mt = 0; mt < 4; ++mt) {
        pkk[nt][mt][0] = (u32)f2bf(sacc[nt][mt][0]) | ((u32)f2bf(sacc[nt][mt][1]) << 16);
        pkk[nt][mt][1] = (u32)f2bf(sacc[nt][mt][2]) | ((u32)f2bf(sacc[nt][mt][3]) << 16);
      }
    // V^T B-frags
    s16x8 vb[2][2];
#pragma unroll
    for (int nd = 0; nd < 2; ++nd)
#pragma unroll
      for (int s = 0; s < 2; ++s)
        vb[nd][s] = *(const s16x8*)&sVT[(h * 32 + nd * 16 + lr) * SVT_RS + lg * 8 + 32 * s];
    // PV: redistribute P into A-frag order via shfl (srcA=l+32(g&1), srcB=+16,
    // register mt' = 2s+(g>>1) -> fetch both and select on (il&32))
    const int srcA = lr + ((il & 16) << 1);
    const int srcB = srcA + 16;
    const bool gh = (il & 32) != 0;
    f32x4 oacc[4][2];
#pragma unroll
    for (int mo = 0; mo < 4; ++mo)
#pragma unroll
      for (int nd = 0; nd < 2; ++nd) oacc[mo][nd] = (f32x4){0.f, 0.f, 0.f, 0.f};
#pragma unroll
    for (int mo = 0; mo < 4; ++mo) {
#pragma unroll
      for (int s = 0; s < 2; ++s) {
        u32 a0 = (u32)__shfl((int)pkk[mo][2 * s][0],     srcA, 64);
        u32 b0 = (u32)__shfl((int)pkk[mo][2 * s + 1][0], srcA, 64);
        u32 a1 = (u32)__shfl((int)pkk[mo][2 * s][1],     srcA, 64);
        u32 b1 = (u32)__shfl((int)pkk[mo][2 * s + 1][1], srcA, 64);
        u32 a2 = (u32)__shfl((int)pkk[mo][2 * s][0],     srcB, 64);
        u32 b2 = (u32)__shfl((int)pkk[mo][2 * s + 1][0], srcB, 64);
        u32 a3 = (u32)__shfl((int)pkk[mo][2 * s][1],     srcB, 64);
        u32 b3 = (u32)__shfl((int)pkk[mo][2 * s + 1][1], srcB, 64);
        union { u32 u[4]; s16x8 v; } pu;
        pu.u[0] = gh ? b0 : a0;
        pu.u[1] = gh ? b1 : a1;
        pu.u[2] = gh ? b2 : a2;
        pu.u[3] = gh ? b3 : a3;
#pragma unroll
        for (int nd = 0; nd < 2; ++nd)
          oacc[mo][nd] = __builtin_amdgcn_mfma_f32_16x16x32_bf16(
              pu.v, vb[nd][s], oacc[mo][nd], 0, 0, 0);
      }
    }
    // epilogue: O * (1/sum) -> sX bf16 (A-layout rows for P4)
#pragma unroll
    for (int mo = 0; mo < 4; ++mo) {
      const f32x4 inv4 = *(const f32x4*)&sINV[h * 64 + 16 * mo + 4 * lg];
#pragma unroll
      for (int nd = 0; nd < 2; ++nd)
#pragma unroll
        for (int i = 0; i < 4; ++i) {
          const int q = 16 * mo + 4 * lg + i;
          if (q < NT)
            sX[q * SX_RS + h * 32 + nd * 16 + lr] = f2bf(oacc[mo][nd][i] * inv4[i]);
        }
    }
  }
  __syncthreads();

  // ---- Phase 4: out = attn_out @ proj_w^T + proj_b via MFMA ----
  {
    f32x4 acc[2][4];
#pragma unroll
    for (int nt = 0; nt < 2; ++nt)
#pragma unroll
      for (int mt = 0; mt < 4; ++mt) acc[nt][mt] = (f32x4){0.f, 0.f, 0.f, 0.f};
    const u16* wpb = wp + (size_t)hh * 8192 + il * 8;
#pragma unroll 2
    for (int kk = 0; kk < 8; ++kk) {
      s16x8 a[4], b[2];
#pragma unroll
      for (int mt = 0; mt < 4; ++mt)
        a[mt] = *(const s16x8*)&sX[(mt * 16 + lr) * SX_RS + kk * 32 + lg * 8];
#pragma unroll
      for (int nt = 0; nt < 2; ++nt)
        b[nt] = *(const s16x8*)&wpb[(nt * 8 + kk) * 512];
#pragma unroll
      for (int nt = 0; nt < 2; ++nt)
#pragma unroll
        for (int mt = 0; mt < 4; ++mt)
          acc[nt][mt] = __builtin_amdgcn_mfma_f32_16x16x32_bf16(
              a[mt], b[nt], acc[nt][mt], 0, 0, 0);
    }
    float* og = out + (size_t)wid * (NT * CD);
#pragma unroll
    for (int nt = 0; nt < 2; ++nt) {
      const int col = hh * 32 + nt * 16 + lr;
      const float bias = proj_b[col];
#pragma unroll
      for (int mt = 0; mt < 4; ++mt) {
#pragma unroll
        for (int i = 0; i < 4; ++i) {
          const int row = mt * 16 + lg * 4 + i;
          if (row < NT) og[row * CD + col] = acc[nt][mt][i] + bias;
        }
      }
    }
  }
}

extern "C" void kernel_launch(void* const* d_in, const int* in_sizes, int n_in,
                              void* d_out, int out_size, void* d_ws, size_t ws_size,
                              hipStream_t stream) {
  (void)in_sizes; (void)n_in; (void)out_size; (void)ws_size;
  const float* x           = (const float*)d_in[0];
  const float* qkv_w       = (const float*)d_in[1];
  const float* q_bias      = (const float*)d_in[2];
  const float* v_bias      = (const float*)d_in[3];
  const float* logit_scale = (const float*)d_in[4];
  const float* cpb_w1      = (const float*)d_in[5];
  const float* cpb_b1      = (const float*)d_in[6];
  const float* cpb_w2      = (const float*)d_in[7];
  const float* coords      = (const float*)d_in[8];
  const int*   rpi         = (const int*)d_in[9];
  const float* mask        = (const float*)d_in[10];
  const float* proj_w      = (const float*)d_in[11];
  const float* proj_b      = (const float*)d_in[12];
  float* out = (float*)d_out;

  float* table  = (float*)d_ws;                        // 169*8 f32
  float* rpb64  = (float*)((char*)d_ws + WS_RPB64);    // 8*4096 f32
  float* mask64 = (float*)((char*)d_ws + WS_MSK64);    // 64*4096 f32
  u16*   wq     = (u16*)((char*)d_ws + WS_WQKV);       // 384 KB bf16
  u16*   wp     = (u16*)((char*)d_ws + WS_WPROJ);      // 128 KB bf16

  hipLaunchKernelGGL(cpb_table_kernel, dim3(6), dim3(256), 0, stream,
                     coords, cpb_w1, cpb_b1, cpb_w2, table);
  hipLaunchKernelGGL(bias64_prep, dim3((8 * 4096 + 64 * 4096 + 255) / 256),
                     dim3(256), 0, stream, table, rpi, mask, rpb64, mask64);
  hipLaunchKernelGGL(wcvt_kernel, dim3(128), dim3(256), 0, stream,
                     qkv_w, proj_w, wq, wp);
  hipLaunchKernelGGL(swin_fused, dim3(NWIN), dim3(512), 0, stream,
                     x, q_bias, v_bias, logit_scale, rpb64, mask64,
                     wq, wp, proj_b, out);
}